// Round 2
// baseline (888.481 us; speedup 1.0000x reference)
//
#include <hip/hip_runtime.h>

// CapsuleNetwork routing, fused, one block per batch. B=2048, S=200, D=64, K=4.
//
// hat[b,k,s,:] = emb[b,s,:] @ W_k + b_k is never materialized:
//   logits[k,s] = emb[s]·u[k] + off[k],  u[k] = W_k @ G[k], off[k] = b_k·G[k]
//   v[k]        = e[k] @ W_k + t[k]·b_k, e[k] = sum_s sw[k,s] emb[s]
// G = running sum of interests (cw telescopes).
//
// Round-2 structure: no emb LDS tile (his read from global, L1/L2-cached);
// LDS ~11 KB -> 8 blocks/CU (32 waves, 100% occupancy), whole grid resident.

#define NB 2048
#define NS 200
#define ND 64
#define NK 4

__device__ __forceinline__ float wred64(float v) {
#pragma unroll
  for (int o = 1; o < 64; o <<= 1) v += __shfl_xor(v, o, 64);
  return v;
}

__global__ __launch_bounds__(256, 8) void caps_kernel(
    const float* __restrict__ his, const float* __restrict__ itemeb,
    const int* __restrict__ mask, const float* __restrict__ W,
    const float* __restrict__ bias, float* __restrict__ out) {
  __shared__ float ssw[NS][NK];     // sw[s][k] -- float4 per s
  __shared__ float smsk[NS];
  __shared__ float sG[NK][ND];      // running interest sum (wave-local)
  __shared__ float su[NK][ND];      // u[k] = W_k @ G[k]
  __shared__ float se[NK][ND];      // reduced e[k] (reused for final gather)
  __shared__ float pe[NK][NK][ND];  // partial e: [wave][k][c]
  __shared__ float pts[NK][NK];     // partial sum-of-sw: [wave][k]
  __shared__ float soff[NK];
  __shared__ float satt[NK];
  __shared__ int sidx;

  const int t = threadIdx.x;
  const int w = t >> 6;  // wave id
  const int l = t & 63;  // lane
  const int b = blockIdx.x;
  const float* eb = his + (size_t)b * NS * ND;

  // init: sw(it=0) = 0.25 * mask  (softmax of zeros over K)
  if (t < NS) {
    float m = (mask[b * NS + t] != 0) ? 1.0f : 0.0f;
    smsk[t] = m;
    float v = 0.25f * m;
    float4 sv = {v, v, v, v};
    *(float4*)&ssw[t][0] = sv;
  }
  sG[w][l] = 0.0f;
  __syncthreads();

  for (int it = 0; it < 3; ++it) {
    if (it > 0) {
      // ---- Phase A: u[w][l] = sum_d W[l][w*64+d]*G[w][d]; off[w] = b_w·G[w]
      {
        const float4* Wr = (const float4*)(W + (size_t)l * (NK * ND) + w * ND);
        const float4* Gk = (const float4*)&sG[w][0];  // broadcast reads
        float acc = 0.0f;
#pragma unroll
        for (int d4 = 0; d4 < ND / 4; ++d4) {
          float4 wv = Wr[d4];
          float4 gv = Gk[d4];
          acc += wv.x * gv.x + wv.y * gv.y + wv.z * gv.z + wv.w * gv.w;
        }
        su[w][l] = acc;
        float ob = wred64(bias[w * ND + l] * sG[w][l]);
        if (l == 0) soff[w] = ob;
      }
      __syncthreads();
      // ---- Phase B: thread t == s; 4 logits + thread-local softmax over k
      if (t < NS) {
        float a0 = soff[0], a1 = soff[1], a2 = soff[2], a3 = soff[3];
        const float4* er = (const float4*)(eb + t * ND);
#pragma unroll
        for (int c4 = 0; c4 < ND / 4; ++c4) {
          float4 ev = er[c4];
          float4 u0 = *(const float4*)&su[0][c4 * 4];  // broadcast
          float4 u1 = *(const float4*)&su[1][c4 * 4];
          float4 u2 = *(const float4*)&su[2][c4 * 4];
          float4 u3 = *(const float4*)&su[3][c4 * 4];
          a0 += ev.x * u0.x + ev.y * u0.y + ev.z * u0.z + ev.w * u0.w;
          a1 += ev.x * u1.x + ev.y * u1.y + ev.z * u1.z + ev.w * u1.w;
          a2 += ev.x * u2.x + ev.y * u2.y + ev.z * u2.z + ev.w * u2.w;
          a3 += ev.x * u3.x + ev.y * u3.y + ev.z * u3.z + ev.w * u3.w;
        }
        float m = fmaxf(fmaxf(a0, a1), fmaxf(a2, a3));
        float e0 = expf(a0 - m), e1 = expf(a1 - m), e2 = expf(a2 - m),
              e3 = expf(a3 - m);
        float r = smsk[t] / (e0 + e1 + e2 + e3);
        float4 sv = {e0 * r, e1 * r, e2 * r, e3 * r};
        *(float4*)&ssw[t][0] = sv;
      }
      __syncthreads();
    }

    // ---- Phase D: wave w handles s in [50w, 50w+50); coalesced his reads
    float ac0 = 0.0f, ac1 = 0.0f, ac2 = 0.0f, ac3 = 0.0f;
    float ts0 = 0.0f, ts1 = 0.0f, ts2 = 0.0f, ts3 = 0.0f;
    for (int s = w * (NS / NK); s < (w + 1) * (NS / NK); ++s) {
      float ev = eb[s * ND + l];                    // 256B/wave contiguous
      float4 swv = *(const float4*)&ssw[s][0];      // LDS broadcast b128
      ac0 += swv.x * ev; ac1 += swv.y * ev; ac2 += swv.z * ev; ac3 += swv.w * ev;
      ts0 += swv.x; ts1 += swv.y; ts2 += swv.z; ts3 += swv.w;
    }
    pe[w][0][l] = ac0; pe[w][1][l] = ac1; pe[w][2][l] = ac2; pe[w][3][l] = ac3;
    if (l == 0) { pts[w][0] = ts0; pts[w][1] = ts1; pts[w][2] = ts2; pts[w][3] = ts3; }
    __syncthreads();

    // ---- Reduce partials + Phase E: wave w == k, lane l == output dim d
    float e = pe[0][w][l] + pe[1][w][l] + pe[2][w][l] + pe[3][w][l];
    float ts = pts[0][w] + pts[1][w] + pts[2][w] + pts[3][w];
    se[w][l] = e;  // wave-local write; read below by same wave (lockstep)
    float accv = ts * bias[w * ND + l];
#pragma unroll
    for (int c4 = 0; c4 < ND / 4; ++c4) {
      float4 ev = *(const float4*)&se[w][c4 * 4];  // broadcast
      int c = c4 * 4;
      accv += ev.x * W[(c + 0) * (NK * ND) + w * ND + l];  // 256B/wave coalesced
      accv += ev.y * W[(c + 1) * (NK * ND) + w * ND + l];
      accv += ev.z * W[(c + 2) * (NK * ND) + w * ND + l];
      accv += ev.w * W[(c + 3) * (NK * ND) + w * ND + l];
    }
    float n2 = wred64(accv * accv);
    float scale = n2 / (1.0f + n2) / sqrtf(n2 + 1e-9f);
    float inter = scale * accv;

    if (it < 2) {
      sG[w][l] += inter;  // wave-local; next barrier (phase A) orders reuse
    } else {
      // final interest -> out; readout via argmax of interest·item_eb
      out[((size_t)b * NK + w) * ND + l] = inter;
      float dot = wred64(inter * itemeb[b * ND + l]);
      se[w][l] = inter;  // stash for gather (wave-local overwrite, post-reads)
      if (l == 0) satt[w] = dot;
      __syncthreads();
      if (t == 0) {
        int bi = 0;
        float bv = satt[0];
#pragma unroll
        for (int k = 1; k < NK; ++k)
          if (satt[k] > bv) { bv = satt[k]; bi = k; }  // first-max == np.argmax
        sidx = bi;
      }
      __syncthreads();
      if (t < ND) out[(size_t)NB * NK * ND + (size_t)b * ND + t] = se[sidx][t];
    }
  }
}

extern "C" void kernel_launch(void* const* d_in, const int* in_sizes, int n_in,
                              void* d_out, int out_size, void* d_ws, size_t ws_size,
                              hipStream_t stream) {
  (void)in_sizes; (void)n_in; (void)out_size; (void)d_ws; (void)ws_size;
  const float* his = (const float*)d_in[0];
  const float* itemeb = (const float*)d_in[1];
  const int* mask = (const int*)d_in[2];
  const float* W = (const float*)d_in[3];
  const float* bias = (const float*)d_in[4];
  float* out = (float*)d_out;
  caps_kernel<<<NB, 256, 0, stream>>>(his, itemeb, mask, W, bias, out);
}

// Round 3
// 340.424 us; speedup vs baseline: 2.6099x; 2.6099x over previous
//
#include <hip/hip_runtime.h>

// CapsuleNetwork routing, fused, one block per batch. B=2048, S=200, D=64, K=4.
//
// hat[b,k,s,:] = emb[b,s,:] @ W_k + b_k is never materialized:
//   logits[k,s] = emb[s]·u[k] + off[k],  u[k] = W_k @ G[k], off[k] = b_k·G[k]
//   v[k]        = e[k] @ W_k + t[k]·b_k, e[k] = sum_s sw[k,s] emb[s]
// G = running sum of interests (cw telescopes).
//
// Round-3: emb staged ONCE into LDS via global_load_lds (linear dest,
// chunk-XOR-swizzled global source; reads apply the same swizzle).
// 512 thr/block, LDS ~59KB -> 2 blocks/CU (16 waves/CU).

#define NB 2048
#define NS 200
#define ND 64
#define NK 4
#define NT 512
#define NW 8

__device__ __forceinline__ float wred64(float v) {
#pragma unroll
  for (int o = 1; o < 64; o <<= 1) v += __shfl_xor(v, o, 64);
  return v;
}

__device__ __forceinline__ void gload16(const float* g, float* l) {
#if __has_builtin(__builtin_amdgcn_global_load_lds)
  __builtin_amdgcn_global_load_lds(
      (const __attribute__((address_space(1))) unsigned int*)g,
      (__attribute__((address_space(3))) unsigned int*)l, 16, 0, 0);
#else
  // reg-staging fallback: lane writes its own 16B at base + 16*lane
  int lane = threadIdx.x & 63;
  *(float4*)(l + 4 * lane) = *(const float4*)(g);
#endif
}

__global__ __launch_bounds__(NT, 4) void caps_kernel(
    const float* __restrict__ his, const float* __restrict__ itemeb,
    const int* __restrict__ mask, const float* __restrict__ W,
    const float* __restrict__ bias, float* __restrict__ out) {
  // semb layout: row s, 16B-chunk slot p holds global chunk (p ^ (s&15)).
  __shared__ float semb[NS * ND];   // 51200 B
  __shared__ float ssw[NS][NK];     // 3200 B
  __shared__ float smsk[NS];        // 800 B
  __shared__ float sG[NK][ND];      // 1024 B
  __shared__ float su[NK][ND];      // 1024 B
  __shared__ float se[NK][ND];      // 1024 B
  __shared__ float pe2[2][NK][ND];  // 2048 B
  __shared__ float pts2[2][NK];
  __shared__ float sts[NK];
  __shared__ float soff[NK];
  __shared__ float satt[NK];
  __shared__ int sidx;

  const int t = threadIdx.x;
  const int w = t >> 6;   // wave 0..7
  const int l = t & 63;   // lane
  const int hk = w & 3;   // k for split phases
  const int hh = w >> 2;  // half index
  const int b = blockIdx.x;
  const float* eb = his + (size_t)b * NS * ND;

  // ---- stage emb once: 50 calls x (64 lanes x 16B) = 200 rows ----
  for (int i = w; i < (NS * ND) / 256; i += NW) {
    int f = i * 256 + 4 * l;       // linear LDS float index of this lane
    int s = f >> 6;                // row
    int j = (f >> 2) & 15;         // LDS chunk slot -> global chunk j^(s&15)
    gload16(eb + (s << 6) + ((j ^ (s & 15)) << 2), &semb[i * 256]);
  }
  if (t < NS) {
    float m = (mask[b * NS + t] != 0) ? 1.0f : 0.0f;
    smsk[t] = m;
    float v = 0.25f * m;  // softmax(0) over K = 0.25, masked
    float4 sv = {v, v, v, v};
    *(float4*)&ssw[t][0] = sv;
  }
  __syncthreads();

  for (int it = 0; it < 3; ++it) {
    if (it > 0) {
      // ---- Phase A: waves 0-3: su[k=w][l] = sum_d W[l][k*64+d]*G[k][d];
      //               waves 4-7: soff[k=w-4] = b_k . G[k]
      if (w < 4) {
        const float4* Wr = (const float4*)(W + (size_t)l * (NK * ND) + w * ND);
        const float4* Gk = (const float4*)&sG[w][0];  // broadcast
        float acc = 0.0f;
#pragma unroll
        for (int d4 = 0; d4 < ND / 4; ++d4) {
          float4 wv = Wr[d4];
          float4 gv = Gk[d4];
          acc += wv.x * gv.x + wv.y * gv.y + wv.z * gv.z + wv.w * gv.w;
        }
        su[w][l] = acc;
      } else {
        int k = w - 4;
        float ob = wred64(bias[k * ND + l] * sG[k][l]);
        if (l == 0) soff[k] = ob;
      }
      __syncthreads();

      // ---- Phase B: thread -> (s = p*128 + t>>2, k = t&3); 2 passes
#pragma unroll
      for (int p = 0; p < 2; ++p) {
        int s = p * 128 + (t >> 2);
        int k = t & 3;
        if (s < NS) {
          int sz = s & 15;
          float a = soff[k];
#pragma unroll
          for (int j = 0; j < 16; ++j) {
            float4 ev = *(const float4*)&semb[(s << 6) + ((j ^ sz) << 2)];
            float4 uv = *(const float4*)&su[k][4 * j];  // 4-addr broadcast
            a += ev.x * uv.x + ev.y * uv.y + ev.z * uv.z + ev.w * uv.w;
          }
          // softmax over k within the 4-lane group
          float m = fmaxf(a, __shfl_xor(a, 1, 64));
          m = fmaxf(m, __shfl_xor(m, 2, 64));
          float e = __expf(a - m);
          float sum = e + __shfl_xor(e, 1, 64);
          sum += __shfl_xor(sum, 2, 64);
          ssw[s][k] = (e / sum) * smsk[s];
        }
      }
      __syncthreads();
    }

    // ---- Phase D: wave (hh,hk): partial e[hk][l] over s in [100hh,100hh+100)
    {
      float acc = 0.0f, ts = 0.0f;
      int s0 = hh * (NS / 2);
      for (int s = s0; s < s0 + NS / 2; ++s) {
        int p = (l >> 2) ^ (s & 15);  // lane l reads global c == l
        float ev = semb[(s << 6) + (p << 2) + (l & 3)];  // conflict-free
        float sw = ssw[s][hk];                           // broadcast
        acc += sw * ev;
        ts += sw;
      }
      pe2[hh][hk][l] = acc;
      if (l == 0) pts2[hh][hk] = ts;
    }
    __syncthreads();

    // ---- Combine + Phase E + squash: waves 0-3 only (k = w)
    if (w < 4) {
      float e = pe2[0][w][l] + pe2[1][w][l];
      float ts = pts2[0][w] + pts2[1][w];
      se[w][l] = e;  // wave-local write, wave-local reads below
      float accv = ts * bias[w * ND + l];
      const float* Wc = W + w * ND + l;
#pragma unroll
      for (int c4 = 0; c4 < ND / 4; ++c4) {
        float4 ev = *(const float4*)&se[w][4 * c4];  // broadcast
        int c = 4 * c4;
        accv += ev.x * Wc[(size_t)(c + 0) * (NK * ND)];  // coalesced 256B/wave
        accv += ev.y * Wc[(size_t)(c + 1) * (NK * ND)];
        accv += ev.z * Wc[(size_t)(c + 2) * (NK * ND)];
        accv += ev.w * Wc[(size_t)(c + 3) * (NK * ND)];
      }
      float n2 = wred64(accv * accv);
      float scale = n2 / (1.0f + n2) / sqrtf(n2 + 1e-9f);
      float inter = scale * accv;
      if (it < 2) {
        sG[w][l] = (it == 0) ? inter : (sG[w][l] + inter);
      } else {
        out[((size_t)b * NK + w) * ND + l] = inter;
        float dot = wred64(inter * itemeb[b * ND + l]);
        se[w][l] = inter;  // stash for gather (after all se reads)
        if (l == 0) satt[w] = dot;
      }
    }
    __syncthreads();

    if (it == 2) {
      if (t == 0) {
        int bi = 0;
        float bv = satt[0];
#pragma unroll
        for (int k = 1; k < NK; ++k)
          if (satt[k] > bv) { bv = satt[k]; bi = k; }  // first-max == np.argmax
        sidx = bi;
      }
      __syncthreads();
      if (t < ND) out[(size_t)NB * NK * ND + (size_t)b * ND + t] = se[sidx][t];
    }
  }
}

extern "C" void kernel_launch(void* const* d_in, const int* in_sizes, int n_in,
                              void* d_out, int out_size, void* d_ws, size_t ws_size,
                              hipStream_t stream) {
  (void)in_sizes; (void)n_in; (void)out_size; (void)d_ws; (void)ws_size;
  const float* his = (const float*)d_in[0];
  const float* itemeb = (const float*)d_in[1];
  const int* mask = (const int*)d_in[2];
  const float* W = (const float*)d_in[3];
  const float* bias = (const float*)d_in[4];
  float* out = (float*)d_out;
  caps_kernel<<<NB, NT, 0, stream>>>(his, itemeb, mask, W, bias, out);
}

// Round 4
// 96.807 us; speedup vs baseline: 9.1778x; 3.5165x over previous
//
#include <hip/hip_runtime.h>

// CapsuleNetwork routing, fused, one block per batch. B=2048, S=200, D=64, K=4.
//
// hat[b,k,s,:] = emb[b,s,:] @ W_k + b_k is never materialized:
//   logits[k,s] = emb[s]·u[k] + off[k],  u[k] = W_k @ G[k], off[k] = b_k·G[k]
//   v[k]        = e[k] @ W_k + ts[k]·b_k, e[k] = sum_s sw[k,s] emb[s]
// G = running sum of interests (cw telescopes).
//
// Round-4: LDS-instruction minimization.
//  - semb row-major, 16B chunks rotated by row (slot=(j+s)&15), staged via
//    global_load_lds (linear dest, pre-rotated per-lane global source).
//  - Phase D: 32x 16-lane groups, one b128 per s per lane, float4 acc per k.
//  - Phase B: thread-per-s, in-lane softmax, broadcast su reads (no 4-way bank
//    conflict of round 3).
//  - Phase E: W cached in 32 regs/lane (wave (k,h) owns a 32x64 W slice).
//  - ssw/pe share one LDS pool (disjoint live ranges).

#define NB 2048
#define NS 200
#define ND 64
#define NK 4
#define NT 512

__device__ __forceinline__ float wred64(float v) {
#pragma unroll
  for (int o = 1; o < 64; o <<= 1) v += __shfl_xor(v, o, 64);
  return v;
}

__device__ __forceinline__ void gload16(const float* g_, float* l_) {
  __builtin_amdgcn_global_load_lds(
      (const __attribute__((address_space(1))) unsigned int*)g_,
      (__attribute__((address_space(3))) unsigned int*)l_, 16, 0, 0);
}

#define RED_GRP(v)                 \
  v += __shfl_xor(v, 16, 64);      \
  v += __shfl_xor(v, 32, 64);

__global__ __launch_bounds__(NT, 4) void caps_kernel(
    const float* __restrict__ his, const float* __restrict__ itemeb,
    const int* __restrict__ mask, const float* __restrict__ W,
    const float* __restrict__ bias, float* __restrict__ out) {
  __shared__ float semb[NS * ND];  // 51200B: row s, chunk q at slot (q+s)&15
  __shared__ float upool[2048];    // union: ssw[200][4] | pe[8][4][64]
  __shared__ float se[NK][ND];     // reduced e[k]
  __shared__ float pv[NK][ND];     // E half-1 partials; later interest stash
  __shared__ float sG[NK][ND];     // running interest sum
  __shared__ float su[NK][ND];     // u[k]
  __shared__ float smsk[NS];
  __shared__ float pts[8][NK];     // per-wave sum-of-sw partials
  __shared__ float sts[NK];        // reduced sum-of-sw
  __shared__ float soff[NK];
  __shared__ float satt[NK];
  __shared__ int sidx;

  const int t = threadIdx.x;
  const int w = t >> 6, l = t & 63;
  const int g = l >> 4, j = l & 15;  // 16-lane group / chunk index
  const int gid = (w << 2) | g;      // 0..31
  const int k = w & 3, h = w >> 2;   // E-phase wave role
  const int b = blockIdx.x;
  const float* eb = his + (size_t)b * NS * ND;

  // ---- stage emb once (rotated chunks; linear LDS dest, per-lane gsrc) ----
  for (int i = w; i < 50; i += 8) {
    int s = 4 * i + g;              // row this lane serves
    int q = (j - s) & 15;           // global chunk that belongs at slot j
    gload16(eb + (s << 6) + (q << 2), &semb[i * 256]);
  }
  float wreg[32];  // W[32h+c][64k+l], c = 0..31  (statically indexed)
#pragma unroll
  for (int c = 0; c < 32; ++c)
    wreg[c] = W[(size_t)(32 * h + c) * (NK * ND) + k * ND + l];
  float breg = bias[k * ND + l];
  float iq = itemeb[(size_t)b * ND + l];
  if (t < NS) smsk[t] = (mask[b * NS + t] != 0) ? 1.0f : 0.0f;
  __syncthreads();

  for (int it = 0; it < 3; ++it) {
    if (it > 0) {
      // ---- A: su[k][c] (waves 0-3, W-row dots); off[k]=b_k.G[k] (waves 4-7)
      if (w < 4) {
        const float4* Wr = (const float4*)(W + (size_t)l * (NK * ND) + w * ND);
        const float4* Gk = (const float4*)&sG[w][0];  // broadcast
        float a = 0.f;
#pragma unroll
        for (int d4 = 0; d4 < 16; ++d4) {
          float4 wv = Wr[d4], gv = Gk[d4];
          a += wv.x * gv.x + wv.y * gv.y + wv.z * gv.z + wv.w * gv.w;
        }
        su[w][l] = a;
      } else {
        float ob = wred64(breg * sG[w - 4][l]);  // breg IS bias[(w-4)*64+l]
        if (l == 0) soff[w - 4] = ob;
      }
      __syncthreads();

      // ---- B: thread-per-s, 4 logits, in-lane softmax -> ssw (upool) ----
      if (t < NS) {
        float lg0 = soff[0], lg1 = soff[1], lg2 = soff[2], lg3 = soff[3];
#pragma unroll
        for (int jj = 0; jj < 16; ++jj) {
          float4 eq = *(const float4*)&semb[(t << 6) + 4 * ((jj + t) & 15)];
          float4 u0 = *(const float4*)&su[0][4 * jj];  // broadcast reads
          float4 u1 = *(const float4*)&su[1][4 * jj];
          float4 u2 = *(const float4*)&su[2][4 * jj];
          float4 u3 = *(const float4*)&su[3][4 * jj];
          lg0 += eq.x * u0.x + eq.y * u0.y + eq.z * u0.z + eq.w * u0.w;
          lg1 += eq.x * u1.x + eq.y * u1.y + eq.z * u1.z + eq.w * u1.w;
          lg2 += eq.x * u2.x + eq.y * u2.y + eq.z * u2.z + eq.w * u2.w;
          lg3 += eq.x * u3.x + eq.y * u3.y + eq.z * u3.z + eq.w * u3.w;
        }
        float m = fmaxf(fmaxf(lg0, lg1), fmaxf(lg2, lg3));
        float e0 = __expf(lg0 - m), e1 = __expf(lg1 - m);
        float e2 = __expf(lg2 - m), e3 = __expf(lg3 - m);
        float r = smsk[t] / (e0 + e1 + e2 + e3);
        *(float4*)&upool[t * 4] = make_float4(e0 * r, e1 * r, e2 * r, e3 * r);
      }
      __syncthreads();
    }

    // ---- D: chunk-major sweep; group gid covers s = gid + 32*tt ----
    float4 a0 = {0, 0, 0, 0}, a1 = {0, 0, 0, 0}, a2 = {0, 0, 0, 0},
           a3 = {0, 0, 0, 0};
    float t0 = 0, t1 = 0, t2 = 0, t3 = 0;
    const int nt_ = (w < 2) ? 7 : 6;  // wave-uniform trip count
    for (int tt = 0; tt < nt_; ++tt) {
      int s = gid + 32 * tt;
      float4 eq = *(const float4*)&semb[(s << 6) + 4 * ((j + s) & 15)];
      if (it == 0) {
        float swa = 0.25f * smsk[s];  // softmax(0) over K, masked
        a0.x += swa * eq.x; a0.y += swa * eq.y;
        a0.z += swa * eq.z; a0.w += swa * eq.w;
        t0 += swa;
      } else {
        float4 s4 = *(const float4*)&upool[s * 4];  // broadcast
        a0.x += s4.x * eq.x; a0.y += s4.x * eq.y; a0.z += s4.x * eq.z; a0.w += s4.x * eq.w;
        a1.x += s4.y * eq.x; a1.y += s4.y * eq.y; a1.z += s4.y * eq.z; a1.w += s4.y * eq.w;
        a2.x += s4.z * eq.x; a2.y += s4.z * eq.y; a2.z += s4.z * eq.z; a2.w += s4.z * eq.w;
        a3.x += s4.w * eq.x; a3.y += s4.w * eq.y; a3.z += s4.w * eq.z; a3.w += s4.w * eq.w;
        t0 += s4.x; t1 += s4.y; t2 += s4.z; t3 += s4.w;
      }
    }
    if (it > 0) __syncthreads();  // all ssw reads done before pe overwrites pool

    // group-reduce (sum over g: lanes ^16, ^32), then pe/pts write
    RED_GRP(a0.x) RED_GRP(a0.y) RED_GRP(a0.z) RED_GRP(a0.w) RED_GRP(t0)
    if (it > 0) {
      RED_GRP(a1.x) RED_GRP(a1.y) RED_GRP(a1.z) RED_GRP(a1.w)
      RED_GRP(a2.x) RED_GRP(a2.y) RED_GRP(a2.z) RED_GRP(a2.w)
      RED_GRP(a3.x) RED_GRP(a3.y) RED_GRP(a3.z) RED_GRP(a3.w)
      RED_GRP(t1) RED_GRP(t2) RED_GRP(t3)
    }
    if (l < 16) {
      *(float4*)&upool[w * 256 + 4 * l] = a0;  // pe[w][0][4l..]
      if (it > 0) {
        *(float4*)&upool[w * 256 + 64 + 4 * l] = a1;
        *(float4*)&upool[w * 256 + 128 + 4 * l] = a2;
        *(float4*)&upool[w * 256 + 192 + 4 * l] = a3;
      }
    }
    if (l == 0) {
      pts[w][0] = t0;
      if (it > 0) { pts[w][1] = t1; pts[w][2] = t2; pts[w][3] = t3; }
    }
    __syncthreads();

    // ---- mini-reduce: se[k][c] = sum_w pe[w][kk][c]; sts[k] ----
    if (w < 4) {
      int kk = (it == 0) ? 0 : w;
      float e = 0.f;
#pragma unroll
      for (int w2 = 0; w2 < 8; ++w2) e += upool[w2 * 256 + kk * 64 + l];
      se[w][l] = e;
      if (l == 0) {
        float s_ = 0.f;
#pragma unroll
        for (int w2 = 0; w2 < 8; ++w2) s_ += pts[w2][kk];
        sts[w] = s_;
      }
    }
    __syncthreads();

    // ---- E: v[k][l] from wreg; halves combine via pv ----
    float vp = 0.f;
#pragma unroll
    for (int q2 = 0; q2 < 8; ++q2) {
      float4 e4 = *(const float4*)&se[k][4 * (8 * h + q2)];  // broadcast
      vp += e4.x * wreg[4 * q2 + 0] + e4.y * wreg[4 * q2 + 1] +
            e4.z * wreg[4 * q2 + 2] + e4.w * wreg[4 * q2 + 3];
    }
    if (h == 1) pv[k][l] = vp;
    __syncthreads();

    if (h == 0) {
      float accv = vp + pv[k][l] + sts[k] * breg;
      float n2 = wred64(accv * accv);
      float scale = n2 / (1.f + n2) / sqrtf(n2 + 1e-9f);
      float inter = scale * accv;
      if (it < 2) {
        sG[k][l] = (it == 0) ? inter : (sG[k][l] + inter);
      } else {
        out[((size_t)b * NK + k) * ND + l] = inter;
        float dot = wred64(inter * iq);
        pv[k][l] = inter;  // stash for argmax gather
        if (l == 0) satt[k] = dot;
      }
    }
    __syncthreads();
  }

  // ---- readout: argmax over interests (first-max == np.argmax) ----
  if (t == 0) {
    int bi = 0;
    float bv = satt[0];
#pragma unroll
    for (int kk = 1; kk < NK; ++kk)
      if (satt[kk] > bv) { bv = satt[kk]; bi = kk; }
    sidx = bi;
  }
  __syncthreads();
  if (t < ND) out[(size_t)NB * NK * ND + (size_t)b * ND + t] = pv[sidx][t];
}

extern "C" void kernel_launch(void* const* d_in, const int* in_sizes, int n_in,
                              void* d_out, int out_size, void* d_ws, size_t ws_size,
                              hipStream_t stream) {
  (void)in_sizes; (void)n_in; (void)out_size; (void)d_ws; (void)ws_size;
  const float* his = (const float*)d_in[0];
  const float* itemeb = (const float*)d_in[1];
  const int* mask = (const int*)d_in[2];
  const float* W = (const float*)d_in[3];
  const float* bias = (const float*)d_in[4];
  float* out = (float*)d_out;
  caps_kernel<<<NB, NT, 0, stream>>>(his, itemeb, mask, W, bias, out);
}